// Round 1
// baseline (114.961 us; speedup 1.0000x reference)
//
#include <hip/hip_runtime.h>

#define NSAMP 32
#define NELEM 307200          // 480*640 per sample
#define LAM 0.5f
#define EPS 1e-6f
#define BLOCKS_PER_SAMPLE 32
#define THREADS 256

// ws layout: ws[b*3 + 0] = sum(ld), ws[b*3 + 1] = sum(ld^2), ws[b*3 + 2] = count

__global__ __launch_bounds__(THREADS)
void sill_partial(const float* __restrict__ pred,
                  const float* __restrict__ targ,
                  float* __restrict__ ws) {
    const int b     = blockIdx.y;
    const int chunk = blockIdx.x;
    const int tid   = threadIdx.x;

    const int f4_per_sample = NELEM / 4;                     // 76800
    const int f4_per_block  = f4_per_sample / BLOCKS_PER_SAMPLE; // 2400

    const float4* p4 = (const float4*)(pred + (size_t)b * NELEM) + (size_t)chunk * f4_per_block;
    const float4* t4 = (const float4*)(targ + (size_t)b * NELEM) + (size_t)chunk * f4_per_block;

    float s1 = 0.f, s2 = 0.f;
    int   c  = 0;

    for (int i = tid; i < f4_per_block; i += THREADS) {
        float4 p = p4[i];
        float4 t = t4[i];
        if (t.x > 0.f) { float ld = logf(p.x + EPS) - logf(t.x + EPS); s1 += ld; s2 += ld * ld; ++c; }
        if (t.y > 0.f) { float ld = logf(p.y + EPS) - logf(t.y + EPS); s1 += ld; s2 += ld * ld; ++c; }
        if (t.z > 0.f) { float ld = logf(p.z + EPS) - logf(t.z + EPS); s1 += ld; s2 += ld * ld; ++c; }
        if (t.w > 0.f) { float ld = logf(p.w + EPS) - logf(t.w + EPS); s1 += ld; s2 += ld * ld; ++c; }
    }

    // wave-64 reduction
    #pragma unroll
    for (int off = 32; off > 0; off >>= 1) {
        s1 += __shfl_down(s1, off);
        s2 += __shfl_down(s2, off);
        c  += __shfl_down(c,  off);
    }

    __shared__ float sh1[THREADS / 64];
    __shared__ float sh2[THREADS / 64];
    __shared__ int   shc[THREADS / 64];
    const int wave = tid >> 6;
    if ((tid & 63) == 0) { sh1[wave] = s1; sh2[wave] = s2; shc[wave] = c; }
    __syncthreads();

    if (tid == 0) {
        float a1 = 0.f, a2 = 0.f;
        int   ac = 0;
        #pragma unroll
        for (int w = 0; w < THREADS / 64; ++w) { a1 += sh1[w]; a2 += sh2[w]; ac += shc[w]; }
        atomicAdd(&ws[b * 3 + 0], a1);
        atomicAdd(&ws[b * 3 + 1], a2);
        atomicAdd(&ws[b * 3 + 2], (float)ac);
    }
}

__global__ __launch_bounds__(64)
void sill_final(const float* __restrict__ ws, float* __restrict__ out) {
    const int tid = threadIdx.x;
    float v = 0.f;
    if (tid < NSAMP) {
        float s1  = ws[tid * 3 + 0];
        float s2  = ws[tid * 3 + 1];
        float cnt = ws[tid * 3 + 2];
        float sc  = fmaxf(cnt, 1.f);
        float ml  = s1 / sc;
        float ms  = s2 / sc;
        float ps  = ms - LAM * ml * ml;
        v = (cnt > 0.f) ? ps : 0.f;
    }
    #pragma unroll
    for (int off = 32; off > 0; off >>= 1) v += __shfl_down(v, off);
    if (tid == 0) out[0] = v / (float)NSAMP;
}

extern "C" void kernel_launch(void* const* d_in, const int* in_sizes, int n_in,
                              void* d_out, int out_size, void* d_ws, size_t ws_size,
                              hipStream_t stream) {
    const float* pred = (const float*)d_in[0];
    const float* targ = (const float*)d_in[1];
    float* out = (float*)d_out;
    float* ws  = (float*)d_ws;

    // d_ws is re-poisoned (0xAA) before every timed launch; zero the atomic targets.
    hipMemsetAsync(ws, 0, NSAMP * 3 * sizeof(float), stream);

    dim3 grid(BLOCKS_PER_SAMPLE, NSAMP);
    sill_partial<<<grid, THREADS, 0, stream>>>(pred, targ, ws);
    sill_final<<<1, 64, 0, stream>>>(ws, out);
}

// Round 2
// 106.279 us; speedup vs baseline: 1.0817x; 1.0817x over previous
//
#include <hip/hip_runtime.h>

#define NSAMP 32
#define NELEM 307200          // 480*640 per sample
#define LAM 0.5f
#define EPS 1e-6f
#define BLOCKS_PER_SAMPLE 32
#define THREADS 256

// ws layout: float4 per block, index [sample * 32 + chunk] = {sum_ld, sum_ld2, cnt, 0}

__global__ __launch_bounds__(THREADS)
void sill_partial(const float* __restrict__ pred,
                  const float* __restrict__ targ,
                  float4* __restrict__ ws) {
    const int b     = blockIdx.y;   // sample
    const int chunk = blockIdx.x;   // chunk within sample
    const int tid   = threadIdx.x;

    const int f4_per_sample = NELEM / 4;                         // 76800
    const int f4_per_block  = f4_per_sample / BLOCKS_PER_SAMPLE; // 2400

    const float4* p4 = (const float4*)(pred + (size_t)b * NELEM) + (size_t)chunk * f4_per_block;
    const float4* t4 = (const float4*)(targ + (size_t)b * NELEM) + (size_t)chunk * f4_per_block;

    float s1 = 0.f, s2 = 0.f, c = 0.f;

    for (int i = tid; i < f4_per_block; i += THREADS) {
        float4 p = p4[i];
        float4 t = t4[i];
        if (t.x > 0.f) { float ld = __logf(p.x + EPS) - __logf(t.x + EPS); s1 += ld; s2 += ld * ld; c += 1.f; }
        if (t.y > 0.f) { float ld = __logf(p.y + EPS) - __logf(t.y + EPS); s1 += ld; s2 += ld * ld; c += 1.f; }
        if (t.z > 0.f) { float ld = __logf(p.z + EPS) - __logf(t.z + EPS); s1 += ld; s2 += ld * ld; c += 1.f; }
        if (t.w > 0.f) { float ld = __logf(p.w + EPS) - __logf(t.w + EPS); s1 += ld; s2 += ld * ld; c += 1.f; }
    }

    // wave-64 reduction
    #pragma unroll
    for (int off = 32; off > 0; off >>= 1) {
        s1 += __shfl_down(s1, off);
        s2 += __shfl_down(s2, off);
        c  += __shfl_down(c,  off);
    }

    __shared__ float sh1[THREADS / 64];
    __shared__ float sh2[THREADS / 64];
    __shared__ float shc[THREADS / 64];
    const int wave = tid >> 6;
    if ((tid & 63) == 0) { sh1[wave] = s1; sh2[wave] = s2; shc[wave] = c; }
    __syncthreads();

    if (tid == 0) {
        float a1 = 0.f, a2 = 0.f, ac = 0.f;
        #pragma unroll
        for (int w = 0; w < THREADS / 64; ++w) { a1 += sh1[w]; a2 += sh2[w]; ac += shc[w]; }
        ws[b * BLOCKS_PER_SAMPLE + chunk] = make_float4(a1, a2, ac, 0.f);
    }
}

// One block, 1024 threads: thread t owns partial [sample = t>>5, chunk = t&31].
__global__ __launch_bounds__(1024)
void sill_final(const float4* __restrict__ ws, float* __restrict__ out) {
    const int t = threadIdx.x;
    float4 part = ws[t];

    // reduce the 32 chunks of each sample (width-32 shuffles stay within the sample)
    #pragma unroll
    for (int off = 16; off > 0; off >>= 1) {
        part.x += __shfl_down(part.x, off, 32);
        part.y += __shfl_down(part.y, off, 32);
        part.z += __shfl_down(part.z, off, 32);
    }

    __shared__ float ps_sh[NSAMP];
    if ((t & 31) == 0) {
        float cnt = part.z;
        float sc  = fmaxf(cnt, 1.f);
        float ml  = part.x / sc;
        float ms  = part.y / sc;
        float ps  = ms - LAM * ml * ml;
        ps_sh[t >> 5] = (cnt > 0.f) ? ps : 0.f;
    }
    __syncthreads();

    if (t < 64) {
        float v = (t < NSAMP) ? ps_sh[t] : 0.f;
        #pragma unroll
        for (int off = 32; off > 0; off >>= 1) v += __shfl_down(v, off);
        if (t == 0) out[0] = v / (float)NSAMP;
    }
}

extern "C" void kernel_launch(void* const* d_in, const int* in_sizes, int n_in,
                              void* d_out, int out_size, void* d_ws, size_t ws_size,
                              hipStream_t stream) {
    const float* pred = (const float*)d_in[0];
    const float* targ = (const float*)d_in[1];
    float* out  = (float*)d_out;
    float4* ws  = (float4*)d_ws;

    dim3 grid(BLOCKS_PER_SAMPLE, NSAMP);
    sill_partial<<<grid, THREADS, 0, stream>>>(pred, targ, ws);
    sill_final<<<1, 1024, 0, stream>>>(ws, out);
}